// Round 5
// baseline (324.701 us; speedup 1.0000x reference)
//
#include <hip/hip_runtime.h>
#include <hip/hip_fp16.h>

// SiameseEdgeConvNet: 2-layer EdgeConv (max aggr) on two graphs, shared weights.
// N=50000, E=1.6e6, dims 32 -> 64 -> 64.
//
// Algebra: msg = relu([xi, xj-xi] @ W + b) = relu(xi@A + xj@B + b),
//   A=W_lo-W_hi, B=W_hi.  u = x@A + b, v = x@B per node; ReLU monotone =>
//   out[d] = relu(u[d] + max_{e: dst=d} v[src_e]);  empty segment -> 0
//   (matches jax isfinite->0 fixup).  PReLU input >= 0 -> identity -> skipped.
//
// R17 (post-mortem R15/R16: agg is latency-bound on random vk gathers; the
// 6.4 MB/graph gather set thrashes the 4 MB/XCD L2 -> ~57 MB of HBM refetch.
// Temporal splitting (R15) failed: blocks are unsynchronized, the
// instantaneous working set never shrank):
//   * SPATIAL split: channel-half x XCD. Graph g owns XCDs 4g..4g+3; within
//     them, XCDs {0,1} process channels 0-31, XCDs {2,3} channels 32-63.
//     Every block on an XCD gathers ONLY from its graph's 3.2 MB vk
//     channel-half -> L2-resident regardless of block timing.
//   * vk packing changed to channel-half-contiguous: uint slot m = ch{m,m+16}
//     (bytes 0-63), slot 16+m = ch{m+32,m+48} (bytes 64-127). gemm emits two
//     coalesced dword stores; agg gathers 16-lane x dword = 64 B half-rows.
//   * agg block = (128-node bucket, ch-half): phase A counting-sort of the
//     bucket's records (scan duplicated x2 across the ch-half pair, +12.8 MB
//     L2-shared reads), phase B one uint accumulator per node via
//     v_pk_max_f16, 8 nodes sequential per 16-lane group, 8 gathers in
//     flight, sentinel-padded lists. Grid 1568 = 6.1 blocks/CU.
//   * bin unchanged from R16 (TILE=128, EPT=8) - it left the top-5.

constexpr int HID   = 64;
constexpr int TILE  = 128;          // nodes per bin bucket (dst >> 7)
constexpr int TSH   = 7;            // log2(TILE)
constexpr int CAP   = 5120;         // records per bucket (mean 4096, +16s)
constexpr int MAXNB = 512;          // max buckets (N <= 65536)
constexpr int EPT   = 8;            // edges per thread in bin_kernel
constexpr int CAPN  = 96;           // per-node capacity (mean deg 32, max ~70)

typedef _Float16 half8 __attribute__((ext_vector_type(8)));
typedef float    f32x4 __attribute__((ext_vector_type(4)));

__device__ __forceinline__ unsigned int pkmax(unsigned int a, unsigned int b) {
    unsigned int d;
    asm("v_pk_max_f16 %0, %1, %2" : "=v"(d) : "v"(a), "v"(b));
    return d;
}
__device__ __forceinline__ unsigned int f2hbits(float f) {
    const __half h = __float2half_rn(f);
    return (unsigned int)*reinterpret_cast<const unsigned short*>(&h);
}
__device__ __forceinline__ float h2f(unsigned int b16) {
    const unsigned short b = (unsigned short)b16;
    __half h;
    *reinterpret_cast<unsigned short*>(&h) = b;
    return __half2float(h);
}

struct G {                    // one graph's pointer set
    const float* x;           // [N,32] layer-1 input
    const int*   src;         // [E]
    const int*   dst;         // [E]
    int* bcnt;                // [NB]       bucket fill counters
    unsigned int* bin;        // [NB*CAP]   packed records (src<<7 | dst&127)
    float*          u;        // [N,64] fp32
    unsigned short* vk;       // [(N+1),64] fp16, half-contiguous permute:
                              //   uint slot m = ch{m,m+16}, slot 16+m =
                              //   ch{m+32,m+48}; row N = -inf sentinel
    float*          out;      // [N,64] — h after layer 1, final after layer 2
};

// ---- weight prep + vk sentinel row init ----
__global__ __launch_bounds__(256) void prep_w_kernel(
    const float* __restrict__ W1, const float* __restrict__ W2,
    _Float16* __restrict__ Wc1, _Float16* __restrict__ Wc2,
    unsigned short* __restrict__ vkS0, unsigned short* __restrict__ vkS1, int N)
{
    const int i = blockIdx.x * 256 + threadIdx.x;
    if (i < 32 * 64) {
        const int k = i >> 6, c = i & 63;
        const float lo = W1[k * 64 + c], hi = W1[(32 + k) * 64 + c];
        Wc1[k * 128 + c]      = (_Float16)(lo - hi);
        Wc1[k * 128 + 64 + c] = (_Float16)hi;
    }
    const int j = i - 32 * 64;
    if (j >= 0 && j < 64 * 64) {
        const int k = j >> 6, c = j & 63;
        const float lo = W2[k * 64 + c], hi = W2[(64 + k) * 64 + c];
        Wc2[k * 128 + c]      = (_Float16)(lo - hi);
        Wc2[k * 128 + 64 + c] = (_Float16)hi;
    }
    const int q = i - (32 * 64 + 64 * 64);
    if (q >= 0 && q < 2 * HID) {                 // sentinel rows = -inf fp16
        if (q < HID) vkS0[(size_t)N * HID + q]       = 0xFC00u;
        else         vkS1[(size_t)N * HID + (q-HID)] = 0xFC00u;
    }
}

// ---- bin: block-reserved capacity scatter of packed records ----
__global__ __launch_bounds__(256) void bin_kernel(G g0, G g1, int E, int NB) {
    const G g = blockIdx.y ? g1 : g0;
    __shared__ int lh[MAXNB];   // local hist, then local write offset
    __shared__ int lb[MAXNB];   // reserved base per bucket
    for (int i = threadIdx.x; i < NB; i += 256) lh[i] = 0;
    __syncthreads();

    const int base = blockIdx.x * 256 * EPT;
    unsigned int rec[EPT];
    int bb[EPT];
    #pragma unroll
    for (int k = 0; k < EPT; ++k) {
        const int i = base + k * 256 + threadIdx.x;   // coalesced stream
        if (i < E) {
            const int d = g.dst[i];
            const int s = g.src[i];
            rec[k] = ((unsigned int)s << TSH) | (unsigned int)(d & (TILE - 1));
            bb[k]  = d >> TSH;
            atomicAdd(&lh[bb[k]], 1);
        } else bb[k] = -1;
    }
    __syncthreads();
    for (int t = threadIdx.x; t < NB; t += 256) {
        const int c = lh[t];
        lb[t] = c ? atomicAdd(&g.bcnt[t], c) : 0;   // global range reservation
        lh[t] = 0;
    }
    __syncthreads();
    #pragma unroll
    for (int k = 0; k < EPT; ++k) {
        if (bb[k] >= 0) {
            const int off = atomicAdd(&lh[bb[k]], 1);
            const int pos = lb[bb[k]] + off;
            if (pos < CAP)                            // 16-sigma guard
                g.bin[(size_t)bb[k] * CAP + pos] = rec[k];
        }
    }
}

// ---- MFMA node GEMM: [u|v](N x 128) = in(N x K) @ Wc(K x 128); u += bias ----
// v emitted as raw fp16, half-contiguous permute: uint slot m = ch{m,m+16},
// slot 16+m = ch{m+32,m+48}.
template<int K>
__global__ __launch_bounds__(256) void gemm_mfma_kernel(
    G g0, G g1, const _Float16* __restrict__ Wc,
    const float* __restrict__ bias, int N)
{
    const G g = blockIdx.y ? g1 : g0;
    constexpr int KH = K / 32;                 // k-halves (1 or 2)
    const int lane = threadIdx.x & 63;
    const int m    = lane & 15;                // A row / D col-lane
    const int quad = lane >> 4;
    const int wid  = (blockIdx.x * 256 + threadIdx.x) >> 6;
    const int nW   = (gridDim.x * 256) >> 6;

    // B-frags: B[k=32h+quad*8+j][n=16t+m]
    half8 bf[8][KH];
    #pragma unroll
    for (int t = 0; t < 8; ++t)
        #pragma unroll
        for (int h = 0; h < KH; ++h)
            #pragma unroll
            for (int j = 0; j < 8; ++j)
                bf[t][h][j] = Wc[(h * 32 + quad * 8 + j) * 128 + t * 16 + m];

    float bv[4];
    #pragma unroll
    for (int t = 0; t < 4; ++t) bv[t] = bias[t * 16 + m];

    const float* __restrict__ inp = (K == 32) ? g.x : g.out;
    const int tiles = (N + 15) / 16;

    for (int tile = wid; tile < tiles; tile += nW) {
        const int nbase = tile * 16;
        const int nodeA = min(nbase + m, N - 1);
        const float4* rp = (const float4*)(inp + (size_t)nodeA * K);

        half8 a[KH];
        #pragma unroll
        for (int h = 0; h < KH; ++h) {
            const float4 f0 = rp[h * 8 + quad * 2];
            const float4 f1 = rp[h * 8 + quad * 2 + 1];
            a[h][0] = (_Float16)f0.x; a[h][1] = (_Float16)f0.y;
            a[h][2] = (_Float16)f0.z; a[h][3] = (_Float16)f0.w;
            a[h][4] = (_Float16)f1.x; a[h][5] = (_Float16)f1.y;
            a[h][6] = (_Float16)f1.z; a[h][7] = (_Float16)f1.w;
        }

        f32x4 acc[8];
        #pragma unroll
        for (int t = 0; t < 8; ++t) {
            acc[t] = (f32x4){0.f, 0.f, 0.f, 0.f};
            #pragma unroll
            for (int h = 0; h < KH; ++h)
                acc[t] = __builtin_amdgcn_mfma_f32_16x16x32_f16(
                    a[h], bf[t][h], acc[t], 0, 0, 0);
        }

        // D[m=quad*4+r][n=lane&15]
        #pragma unroll
        for (int r = 0; r < 4; ++r) {
            const int node = nbase + quad * 4 + r;
            if (node < N) {
                float* urow = g.u + (size_t)node * HID;
                #pragma unroll
                for (int t = 0; t < 4; ++t)
                    urow[t * 16 + m] = acc[t][r] + bv[t];
                const unsigned int e0 = f2hbits(acc[4][r]);   // channel m
                const unsigned int e1 = f2hbits(acc[5][r]);   // channel m+16
                const unsigned int e2 = f2hbits(acc[6][r]);   // channel m+32
                const unsigned int e3 = f2hbits(acc[7][r]);   // channel m+48
                unsigned int* vr = (unsigned int*)(g.vk + (size_t)node * HID);
                vr[m]      = (e1 << 16) | e0;   // bytes 0-63:  ch 0-31
                vr[16 + m] = (e3 << 16) | e2;   // bytes 64-127: ch 32-63
            }
        }
    }
}

// ---- aggregate: block = (128-node bucket, channel-half) ----
// XCD partition (two=1): xcd = bid&7; graph = xcd>>2; ch-half = (xcd>>1)&1.
// Every block on an XCD gathers only from its graph's 3.2 MB vk ch-half ->
// L2-resident (4 MB/XCD) independent of block timing.
// Phase A: counting-sort bucket records into lrec[128][96], sentinel-pad x8.
// Phase B: 16-lane group, 8 sequential nodes; one uint accumulator per node;
// 64 B half-row gathers (16 lanes x dword), 8 in flight, v_pk_max_f16.
__global__ __launch_bounds__(256) void agg_kernel(G g0, G g1, int N, int NB, int two) {
    int b, h, gi;
    if (two) {
        const int bid = blockIdx.x;
        const int xcd = bid & 7;
        gi = xcd >> 2;               // XCD 0-3: graph 0, XCD 4-7: graph 1
        h  = (xcd >> 1) & 1;         // channel-half
        b  = (bid >> 3) * 2 + (xcd & 1);
    } else { gi = 0; h = blockIdx.x & 1; b = blockIdx.x >> 1; }
    if (b >= NB) return;
    const G g = gi ? g1 : g0;

    __shared__ int lcnt[TILE];
    __shared__ unsigned short lrec[TILE][CAPN];   // 24 KB, rows 16B-aligned
    for (int i = threadIdx.x; i < TILE; i += 256) lcnt[i] = 0;
    __syncthreads();

    const int cnt = min(g.bcnt[b], CAP);
    const unsigned int* __restrict__ bp = g.bin + (size_t)b * CAP;
    for (int i = threadIdx.x; i < cnt; i += 256) {
        const unsigned int rec = bp[i];
        const int d = rec & (TILE - 1);
        const int p = atomicAdd(&lcnt[d], 1);
        if (p < CAPN) lrec[d][p] = (unsigned short)(rec >> TSH);
    }
    __syncthreads();
    for (int t = threadIdx.x; t < TILE; t += 256) {  // pad to x8 w/ sentinel
        const int c  = min(lcnt[t], CAPN);
        const int cp = (c + 7) & ~7;
        for (int p = c; p < cp; ++p) lrec[t][p] = (unsigned short)N;
        lcnt[t] = cp;
    }
    __syncthreads();

    const int grp  = threadIdx.x >> 4;       // 16 groups of 16 lanes
    const int sub  = threadIdx.x & 15;
    const int slot = h * 16 + sub;           // uint slot within vk row
    const unsigned int* __restrict__ vkU = (const unsigned int*)g.vk;

    #pragma unroll 2
    for (int i = 0; i < 8; ++i) {            // 8 sequential nodes per group
        const int nl = grp + 16 * i;
        const int n  = b * TILE + nl;
        if (n >= N) continue;
        const int cp = lcnt[nl];

        unsigned int m0 = 0xFC00FC00u;       // -inf halves
        for (int j = 0; j < cp; j += 8) {
            const uint4 rq = *(const uint4*)(&lrec[nl][j]);  // 8 recs, bcast
            unsigned int s[8];
            s[0] = rq.x & 0xFFFFu; s[1] = rq.x >> 16;
            s[2] = rq.y & 0xFFFFu; s[3] = rq.y >> 16;
            s[4] = rq.z & 0xFFFFu; s[5] = rq.z >> 16;
            s[6] = rq.w & 0xFFFFu; s[7] = rq.w >> 16;
            unsigned int a[8];
            #pragma unroll
            for (int k = 0; k < 8; ++k) a[k] = vkU[(size_t)s[k] * 32 + slot];
            #pragma unroll
            for (int k = 0; k < 8; ++k) m0 = pkmax(m0, a[k]);
        }

        const bool has = cp > 0;
        const int  cb  = sub + 32 * h;       // channels {cb, cb+16}
        const float* __restrict__ urow = g.u + (size_t)n * HID;
        float* __restrict__ orow = g.out + (size_t)n * HID;
        orow[cb] = has ? fmaxf(urow[cb] + h2f(m0 & 0xFFFFu), 0.f) : 0.f;
        orow[cb + 16] = has ? fmaxf(urow[cb + 16] + h2f(m0 >> 16), 0.f) : 0.f;
    }
}

// ---------------- orchestration ----------------

extern "C" void kernel_launch(void* const* d_in, const int* in_sizes, int n_in,
                              void* d_out, int out_size, void* d_ws, size_t ws_size,
                              hipStream_t stream) {
    const float* x1  = (const float*)d_in[0];
    const int*   ei1 = (const int*)d_in[1];   // [2,E]: src row then dst row
    const float* x2  = (const float*)d_in[2];
    const int*   ei2 = (const int*)d_in[3];
    const float* W1  = (const float*)d_in[4];
    const float* b1  = (const float*)d_in[5];
    // d_in[6] = prelu_a: unused (identity on >=0)
    const float* W2  = (const float*)d_in[7];
    const float* b2  = (const float*)d_in[8];

    const int N  = in_sizes[0] / 32;
    const int E  = in_sizes[1] / 2;
    const int NB = (N + TILE - 1) / TILE;     // 391 for N=50000
    float* out = (float*)d_out;

    const size_t rowB = (size_t)N * HID * sizeof(float);            // 12.8 MB
    const size_t vkB  = ((size_t)(N + 1) * HID * 2 + 63) & ~(size_t)63;
    const size_t binB = ((size_t)NB * CAP * sizeof(int) + 63) & ~(size_t)63;
    const size_t nbB  = ((size_t)(NB + 2) * sizeof(int) + 63) & ~(size_t)63;
    const size_t wc1B = ((size_t)32 * 128 * 2 + 63) & ~(size_t)63;
    const size_t wc2B = ((size_t)64 * 128 * 2 + 63) & ~(size_t)63;

    const int bBlk = (E + 256 * EPT - 1) / (256 * EPT);   // 782 per graph
    const int gBlk = 512;
    const int pBlk = (32 * 64 + 64 * 64 + 2 * HID + 255) / 256;
    const int aggBlk2 = ((NB + 1) / 2) * 8;   // XCD-partitioned 1D grid
    const int aggBlk1 = 2 * NB;

    _Float16* wc1 = nullptr;
    _Float16* wc2 = nullptr;

    auto run = [&](G ga, G gb, int ny) {
        // bcnt arrays contiguous across graphs: one memset when ny==2
        hipMemsetAsync(ga.bcnt, 0, (size_t)ny * nbB, stream);
        bin_kernel <<<dim3(bBlk, ny), 256, 0, stream>>>(ga, gb, E, NB);
        gemm_mfma_kernel<32><<<dim3(gBlk, ny), 256, 0, stream>>>(ga, gb, wc1, b1, N);
        if (ny == 2) agg_kernel<<<aggBlk2, 256, 0, stream>>>(ga, gb, N, NB, 1);
        else         agg_kernel<<<aggBlk1, 256, 0, stream>>>(ga, ga, N, NB, 0);
        gemm_mfma_kernel<64><<<dim3(gBlk, ny), 256, 0, stream>>>(ga, gb, wc2, b2, N);
        if (ny == 2) agg_kernel<<<aggBlk2, 256, 0, stream>>>(ga, gb, N, NB, 1);
        else         agg_kernel<<<aggBlk1, 256, 0, stream>>>(ga, ga, N, NB, 0);
    };

    char* ws = (char*)d_ws;
    const size_t needBoth = 2 * rowB + 2 * vkB + 2 * binB + 2 * nbB + wc1B + wc2B;

    if (ws_size >= needBoth) {
        float* u0 = (float*)ws;                  ws += rowB;
        float* u1 = (float*)ws;                  ws += rowB;
        unsigned int* bin0 = (unsigned int*)ws;  ws += binB;
        unsigned int* bin1 = (unsigned int*)ws;  ws += binB;
        unsigned short* vk0 = (unsigned short*)ws;  ws += vkB;
        unsigned short* vk1 = (unsigned short*)ws;  ws += vkB;
        wc1 = (_Float16*)ws;                     ws += wc1B;
        wc2 = (_Float16*)ws;                     ws += wc2B;
        int* bcnt0 = (int*)ws;                   ws += nbB;
        int* bcnt1 = (int*)ws;                   // contiguous with bcnt0

        G g0{x1, ei1, ei1 + E, bcnt0, bin0, u0, vk0, out};
        G g1{x2, ei2, ei2 + E, bcnt1, bin1, u1, vk1, out + (size_t)N * HID};
        prep_w_kernel<<<pBlk, 256, 0, stream>>>(W1, W2, wc1, wc2, vk0, vk1, N);
        run(g0, g1, 2);
    } else {
        // sequential fallback (~28 MB): one graph's buffers, reused
        float* u = (float*)ws;                   ws += rowB;
        unsigned int* bin = (unsigned int*)ws;   ws += binB;
        unsigned short* vk = (unsigned short*)ws;  ws += vkB;
        wc1 = (_Float16*)ws;                     ws += wc1B;
        wc2 = (_Float16*)ws;                     ws += wc2B;
        int* bcnt = (int*)ws;

        prep_w_kernel<<<pBlk, 256, 0, stream>>>(W1, W2, wc1, wc2, vk, vk, N);
        for (int g = 0; g < 2; ++g) {
            const int* ei = g ? ei2 : ei1;
            G gp{g ? x2 : x1, ei, ei + E, bcnt, bin,
                 u, vk, out + (size_t)g * N * HID};
            run(gp, gp, 1);
        }
    }
}

// Round 6
// 268.410 us; speedup vs baseline: 1.2097x; 1.2097x over previous
//
#include <hip/hip_runtime.h>
#include <hip/hip_fp16.h>

// SiameseEdgeConvNet: 2-layer EdgeConv (max aggr) on two graphs, shared weights.
// N=50000, E=1.6e6, dims 32 -> 64 -> 64.
//
// Algebra: msg = relu([xi, xj-xi] @ W + b) = relu(xi@A + xj@B + b),
//   A=W_lo-W_hi, B=W_hi.  u = x@A + b, v = x@B per node; ReLU monotone =>
//   out[d] = relu(u[d] + max_{e: dst=d} v[src_e]);  empty segment -> 0
//   (matches jax isfinite->0 fixup).  PReLU input >= 0 -> identity -> skipped.
//
// R18 = revert to R14 (the only measured-fast agg: TILE=32, single scan,
// full-row uint2 gathers, 6.6 KB LDS, 48 us) + three counter-backed fixes.
// Ledger of failed agg variants (do NOT retry):
//   - R15 two temporal half-row passes: blocks unsynchronized -> working set
//     never shrank, rows fetched twice. FETCH 114->168 MB, 77 us.
//   - R16 2 blocks/bucket halves: duplicate scan, 55 us.
//   - R17 spatial channel-half x XCD: each 64 B half-gather still pulls a
//     full HBM sector, two XCDs miss the same row -> vk HBM ~2x; duplicate
//     scan again. FETCH 195 MB, 86 us.
// R18 changes:
//   1. bin: EPT 16->8 (R14 bin was GRID-limited: 391x2 blocks = 3/CU, occ
//      23%, 1.8 TB/s latency-bound). Now 782x2 = 6.1/CU. CAP 2048->1280
//      (bucket mean 1024, sd 32, +8 sigma) to shrink workspace.
//   2. agg: 16 gathers in flight per lane (was 8) - lists sentinel-padded to
//      x16, two uint4 record reads + 16 uint2 gathers before the pkmax
//      chain. agg was pure latency-bound (VALU 21%, HBM 34%, occ 57%).
//   3. h between layers stored fp16 row-major (same rounding as gemm64's own
//      cvt): -12.8 MB stores, -12.8 MB loads, no cvt VALU in gemm64 A-load.

constexpr int HID   = 64;
constexpr int TILE  = 32;           // nodes per bucket (dst >> 5)
constexpr int TSH   = 5;            // log2(TILE)
constexpr int CAP   = 1280;         // records per bucket (mean 1024, +8s)
constexpr int MAXNB = 2048;         // max buckets (N <= 65536)
constexpr int EPT   = 8;            // edges per thread in bin_kernel
constexpr int CAPN  = 96;           // per-node capacity (mean deg 32, max ~70)

typedef _Float16 half8 __attribute__((ext_vector_type(8)));
typedef float    f32x4 __attribute__((ext_vector_type(4)));

__device__ __forceinline__ unsigned int pkmax(unsigned int a, unsigned int b) {
    unsigned int d;
    asm("v_pk_max_f16 %0, %1, %2" : "=v"(d) : "v"(a), "v"(b));
    return d;
}
__device__ __forceinline__ unsigned int f2hbits(float f) {
    const __half h = __float2half_rn(f);
    return (unsigned int)*reinterpret_cast<const unsigned short*>(&h);
}
__device__ __forceinline__ float h2f(unsigned int b16) {
    const unsigned short b = (unsigned short)b16;
    __half h;
    *reinterpret_cast<unsigned short*>(&h) = b;
    return __half2float(h);
}

struct G {                    // one graph's pointer set
    const float* x;           // [N,32] layer-1 input
    const int*   src;         // [E]
    const int*   dst;         // [E]
    int* bcnt;                // [NB]       bucket fill counters
    unsigned int* bin;        // [NB*CAP]   packed records (src<<5 | dst&31)
    float*          u;        // [N,64] fp32
    unsigned short* vk;       // [(N+1),64] fp16, permuted: uint2 slot m of a
                              //   row holds channels {m, m+16, m+32, m+48};
                              //   row N = -inf sentinel (set once in prep_w)
    _Float16*       h;        // [N,64] fp16 row-major — layer-1 output
    float*          out;      // [N,64] fp32 — final output
};

// ---- weight prep + vk sentinel row init ----
__global__ __launch_bounds__(256) void prep_w_kernel(
    const float* __restrict__ W1, const float* __restrict__ W2,
    _Float16* __restrict__ Wc1, _Float16* __restrict__ Wc2,
    unsigned short* __restrict__ vkS0, unsigned short* __restrict__ vkS1, int N)
{
    const int i = blockIdx.x * 256 + threadIdx.x;
    if (i < 32 * 64) {
        const int k = i >> 6, c = i & 63;
        const float lo = W1[k * 64 + c], hi = W1[(32 + k) * 64 + c];
        Wc1[k * 128 + c]      = (_Float16)(lo - hi);
        Wc1[k * 128 + 64 + c] = (_Float16)hi;
    }
    const int j = i - 32 * 64;
    if (j >= 0 && j < 64 * 64) {
        const int k = j >> 6, c = j & 63;
        const float lo = W2[k * 64 + c], hi = W2[(64 + k) * 64 + c];
        Wc2[k * 128 + c]      = (_Float16)(lo - hi);
        Wc2[k * 128 + 64 + c] = (_Float16)hi;
    }
    const int q = i - (32 * 64 + 64 * 64);
    if (q >= 0 && q < 2 * HID) {                 // sentinel rows = -inf fp16
        if (q < HID) vkS0[(size_t)N * HID + q]       = 0xFC00u;
        else         vkS1[(size_t)N * HID + (q-HID)] = 0xFC00u;
    }
}

// ---- bin: block-reserved capacity scatter of packed records ----
__global__ __launch_bounds__(256) void bin_kernel(G g0, G g1, int E, int NB) {
    const G g = blockIdx.y ? g1 : g0;
    __shared__ int lh[MAXNB];   // local hist, then local write offset
    __shared__ int lb[MAXNB];   // reserved base per bucket
    for (int i = threadIdx.x; i < NB; i += 256) lh[i] = 0;
    __syncthreads();

    const int base = blockIdx.x * 256 * EPT;
    unsigned int rec[EPT];
    int bb[EPT];
    #pragma unroll
    for (int k = 0; k < EPT; ++k) {
        const int i = base + k * 256 + threadIdx.x;   // coalesced stream
        if (i < E) {
            const int d = g.dst[i];
            const int s = g.src[i];
            rec[k] = ((unsigned int)s << TSH) | (unsigned int)(d & (TILE - 1));
            bb[k]  = d >> TSH;
            atomicAdd(&lh[bb[k]], 1);
        } else bb[k] = -1;
    }
    __syncthreads();
    for (int t = threadIdx.x; t < NB; t += 256) {
        const int c = lh[t];
        lb[t] = c ? atomicAdd(&g.bcnt[t], c) : 0;   // global range reservation
        lh[t] = 0;
    }
    __syncthreads();
    #pragma unroll
    for (int k = 0; k < EPT; ++k) {
        if (bb[k] >= 0) {
            const int off = atomicAdd(&lh[bb[k]], 1);
            const int pos = lb[bb[k]] + off;
            if (pos < CAP)                            // 8-sigma guard
                g.bin[(size_t)bb[k] * CAP + pos] = rec[k];
        }
    }
}

// ---- MFMA node GEMM: [u|v](N x 128) = in(N x K) @ Wc(K x 128); u += bias ----
// IN16=false: input = g.x fp32.  IN16=true (K=64): input = g.h fp16 row-major.
// v emitted as raw fp16, permuted: uint2 slot m of a row holds channels
// {m, m+16, m+32, m+48}.
template<int K, bool IN16>
__global__ __launch_bounds__(256) void gemm_mfma_kernel(
    G g0, G g1, const _Float16* __restrict__ Wc,
    const float* __restrict__ bias, int N)
{
    const G g = blockIdx.y ? g1 : g0;
    constexpr int KH = K / 32;                 // k-halves (1 or 2)
    const int lane = threadIdx.x & 63;
    const int m    = lane & 15;                // A row / D col-lane
    const int quad = lane >> 4;
    const int wid  = (blockIdx.x * 256 + threadIdx.x) >> 6;
    const int nW   = (gridDim.x * 256) >> 6;

    // B-frags: B[k=32h+quad*8+j][n=16t+m]
    half8 bf[8][KH];
    #pragma unroll
    for (int t = 0; t < 8; ++t)
        #pragma unroll
        for (int hh = 0; hh < KH; ++hh)
            #pragma unroll
            for (int j = 0; j < 8; ++j)
                bf[t][hh][j] = Wc[(hh * 32 + quad * 8 + j) * 128 + t * 16 + m];

    float bv[4];
    #pragma unroll
    for (int t = 0; t < 4; ++t) bv[t] = bias[t * 16 + m];

    const int tiles = (N + 15) / 16;

    for (int tile = wid; tile < tiles; tile += nW) {
        const int nbase = tile * 16;
        const int nodeA = min(nbase + m, N - 1);

        half8 a[KH];
        if constexpr (IN16) {
            const half8* rp = (const half8*)(g.h + (size_t)nodeA * K);
            #pragma unroll
            for (int hh = 0; hh < KH; ++hh) a[hh] = rp[hh * 4 + quad];
        } else {
            const float4* rp = (const float4*)(g.x + (size_t)nodeA * K);
            #pragma unroll
            for (int hh = 0; hh < KH; ++hh) {
                const float4 f0 = rp[hh * 8 + quad * 2];
                const float4 f1 = rp[hh * 8 + quad * 2 + 1];
                a[hh][0] = (_Float16)f0.x; a[hh][1] = (_Float16)f0.y;
                a[hh][2] = (_Float16)f0.z; a[hh][3] = (_Float16)f0.w;
                a[hh][4] = (_Float16)f1.x; a[hh][5] = (_Float16)f1.y;
                a[hh][6] = (_Float16)f1.z; a[hh][7] = (_Float16)f1.w;
            }
        }

        f32x4 acc[8];
        #pragma unroll
        for (int t = 0; t < 8; ++t) {
            acc[t] = (f32x4){0.f, 0.f, 0.f, 0.f};
            #pragma unroll
            for (int hh = 0; hh < KH; ++hh)
                acc[t] = __builtin_amdgcn_mfma_f32_16x16x32_f16(
                    a[hh], bf[t][hh], acc[t], 0, 0, 0);
        }

        // D[m=quad*4+r][n=lane&15]
        #pragma unroll
        for (int r = 0; r < 4; ++r) {
            const int node = nbase + quad * 4 + r;
            if (node < N) {
                float* urow = g.u + (size_t)node * HID;
                #pragma unroll
                for (int t = 0; t < 4; ++t)
                    urow[t * 16 + m] = acc[t][r] + bv[t];
                const unsigned int e0 = f2hbits(acc[4][r]);   // channel m
                const unsigned int e1 = f2hbits(acc[5][r]);   // channel m+16
                const unsigned int e2 = f2hbits(acc[6][r]);   // channel m+32
                const unsigned int e3 = f2hbits(acc[7][r]);   // channel m+48
                uint2 pack;
                pack.x = (e1 << 16) | e0;
                pack.y = (e3 << 16) | e2;
                ((uint2*)(g.vk + (size_t)node * HID))[m] = pack;
            }
        }
    }
}

// ---- aggregate: one block per 32-node bucket (R14 structure) ----
// Phase A: coalesced record read + LDS counting sort into per-node lists,
//   padded to multiples of 16 with sentinel src=N (-inf vk row).
// Phase B: 16-lane group per node (2 sequential), running max in registers
//   via v_pk_max_f16; full-row uint2 gathers, SIXTEEN in flight per lane.
// OUT16=true (layer 1): write h fp16 row-major.  false: write fp32 out.
template<bool OUT16>
__global__ __launch_bounds__(256) void agg_kernel(G g0, G g1, int N, int NB, int two) {
    int b, gi;
    if (two) {                       // XCD partition: bid%8 -> XCD (heuristic)
        const int bid = blockIdx.x;
        const int xcd = bid & 7;
        gi = xcd >> 2;               // XCD 0-3: graph 0, XCD 4-7: graph 1
        b  = (bid >> 3) * 4 + (xcd & 3);
    } else { gi = 0; b = blockIdx.x; }
    if (b >= NB) return;
    const G g = gi ? g1 : g0;

    __shared__ int lcnt[TILE];
    __shared__ alignas(16) unsigned short lrec[TILE][CAPN];  // 6 KB
    for (int i = threadIdx.x; i < TILE; i += 256) lcnt[i] = 0;
    __syncthreads();

    const int cnt = min(g.bcnt[b], CAP);
    const unsigned int* __restrict__ bp = g.bin + (size_t)b * CAP;
    for (int i = threadIdx.x; i < cnt; i += 256) {
        const unsigned int rec = bp[i];
        const int d = rec & (TILE - 1);
        const int p = atomicAdd(&lcnt[d], 1);
        if (p < CAPN) lrec[d][p] = (unsigned short)(rec >> TSH);
    }
    __syncthreads();
    for (int t = threadIdx.x; t < TILE; t += 256) {   // pad to x16 w/ sentinel
        const int c  = min(lcnt[t], CAPN);
        const int cp = (c + 15) & ~15;
        for (int p = c; p < cp; ++p) lrec[t][p] = (unsigned short)N;
        lcnt[t] = cp;
    }
    __syncthreads();

    const int grp = threadIdx.x >> 4;        // 16 groups of 16 lanes
    const int sub = threadIdx.x & 15;
    const uint2* __restrict__ vk2 = (const uint2*)g.vk;

    #pragma unroll
    for (int i = 0; i < 2; ++i) {
        const int nl = grp + 16 * i;
        const int n  = b * TILE + nl;
        if (n >= N) continue;
        const int cp = lcnt[nl];

        unsigned int m0 = 0xFC00FC00u, m1 = 0xFC00FC00u;   // -inf halves
        for (int j = 0; j < cp; j += 16) {
            const uint4 q0 = *(const uint4*)(&lrec[nl][j]);      // 16 recs,
            const uint4 q1 = *(const uint4*)(&lrec[nl][j + 8]);  // bcast
            unsigned int s[16];
            s[0]  = q0.x & 0xFFFFu; s[1]  = q0.x >> 16;
            s[2]  = q0.y & 0xFFFFu; s[3]  = q0.y >> 16;
            s[4]  = q0.z & 0xFFFFu; s[5]  = q0.z >> 16;
            s[6]  = q0.w & 0xFFFFu; s[7]  = q0.w >> 16;
            s[8]  = q1.x & 0xFFFFu; s[9]  = q1.x >> 16;
            s[10] = q1.y & 0xFFFFu; s[11] = q1.y >> 16;
            s[12] = q1.z & 0xFFFFu; s[13] = q1.z >> 16;
            s[14] = q1.w & 0xFFFFu; s[15] = q1.w >> 16;
            uint2 a[16];
            #pragma unroll
            for (int k = 0; k < 16; ++k) a[k] = vk2[(size_t)s[k] * 16 + sub];
            #pragma unroll
            for (int k = 0; k < 16; ++k) {
                m0 = pkmax(m0, a[k].x);
                m1 = pkmax(m1, a[k].y);
            }
        }

        const bool has = cp > 0;
        const float* __restrict__ urow = g.u + (size_t)n * HID;
        const float r0 = has ? fmaxf(urow[sub]      + h2f(m0 & 0xFFFFu), 0.f) : 0.f;
        const float r1 = has ? fmaxf(urow[sub + 16] + h2f(m0 >> 16),     0.f) : 0.f;
        const float r2 = has ? fmaxf(urow[sub + 32] + h2f(m1 & 0xFFFFu), 0.f) : 0.f;
        const float r3 = has ? fmaxf(urow[sub + 48] + h2f(m1 >> 16),     0.f) : 0.f;
        if constexpr (OUT16) {       // fp16 h, same rounding gemm64 would do
            _Float16* hrow = g.h + (size_t)n * HID;
            hrow[sub]      = (_Float16)r0;
            hrow[sub + 16] = (_Float16)r1;
            hrow[sub + 32] = (_Float16)r2;
            hrow[sub + 48] = (_Float16)r3;
        } else {
            float* __restrict__ orow = g.out + (size_t)n * HID;
            orow[sub]      = r0;
            orow[sub + 16] = r1;
            orow[sub + 32] = r2;
            orow[sub + 48] = r3;
        }
    }
}

// ---------------- orchestration ----------------

extern "C" void kernel_launch(void* const* d_in, const int* in_sizes, int n_in,
                              void* d_out, int out_size, void* d_ws, size_t ws_size,
                              hipStream_t stream) {
    const float* x1  = (const float*)d_in[0];
    const int*   ei1 = (const int*)d_in[1];   // [2,E]: src row then dst row
    const float* x2  = (const float*)d_in[2];
    const int*   ei2 = (const int*)d_in[3];
    const float* W1  = (const float*)d_in[4];
    const float* b1  = (const float*)d_in[5];
    // d_in[6] = prelu_a: unused (identity on >=0)
    const float* W2  = (const float*)d_in[7];
    const float* b2  = (const float*)d_in[8];

    const int N  = in_sizes[0] / 32;
    const int E  = in_sizes[1] / 2;
    const int NB = (N + TILE - 1) / TILE;     // 1563 for N=50000
    float* out = (float*)d_out;

    const size_t rowB = (size_t)N * HID * sizeof(float);            // 12.8 MB
    const size_t vkB  = ((size_t)(N + 1) * HID * 2 + 63) & ~(size_t)63;
    const size_t hB   = ((size_t)N * HID * 2 + 63) & ~(size_t)63;   //  6.4 MB
    const size_t binB = ((size_t)NB * CAP * sizeof(int) + 63) & ~(size_t)63;
    const size_t nbB  = ((size_t)(NB + 2) * sizeof(int) + 63) & ~(size_t)63;
    const size_t wc1B = ((size_t)32 * 128 * 2 + 63) & ~(size_t)63;
    const size_t wc2B = ((size_t)64 * 128 * 2 + 63) & ~(size_t)63;

    const int bBlk = (E + 256 * EPT - 1) / (256 * EPT);   // 782 per graph
    const int gBlk = 512;
    const int pBlk = (32 * 64 + 64 * 64 + 2 * HID + 255) / 256;
    const int aggBlk2 = ((NB + 3) / 4) * 8;   // XCD-partitioned 1D grid
    const int aggBlk1 = NB;

    _Float16* wc1 = nullptr;
    _Float16* wc2 = nullptr;

    auto run = [&](G ga, G gb, int ny) {
        // bcnt arrays contiguous across graphs: one memset when ny==2
        hipMemsetAsync(ga.bcnt, 0, (size_t)ny * nbB, stream);
        bin_kernel <<<dim3(bBlk, ny), 256, 0, stream>>>(ga, gb, E, NB);
        gemm_mfma_kernel<32,false><<<dim3(gBlk, ny), 256, 0, stream>>>(ga, gb, wc1, b1, N);
        if (ny == 2) agg_kernel<true><<<aggBlk2, 256, 0, stream>>>(ga, gb, N, NB, 1);
        else         agg_kernel<true><<<aggBlk1, 256, 0, stream>>>(ga, ga, N, NB, 0);
        gemm_mfma_kernel<64,true><<<dim3(gBlk, ny), 256, 0, stream>>>(ga, gb, wc2, b2, N);
        if (ny == 2) agg_kernel<false><<<aggBlk2, 256, 0, stream>>>(ga, gb, N, NB, 1);
        else         agg_kernel<false><<<aggBlk1, 256, 0, stream>>>(ga, ga, N, NB, 0);
    };

    char* ws = (char*)d_ws;
    const size_t needBoth =
        2 * rowB + 2 * binB + 2 * vkB + 2 * hB + wc1B + wc2B + 2 * nbB;

    if (ws_size >= needBoth) {
        float* u0 = (float*)ws;                  ws += rowB;
        float* u1 = (float*)ws;                  ws += rowB;
        unsigned int* bin0 = (unsigned int*)ws;  ws += binB;
        unsigned int* bin1 = (unsigned int*)ws;  ws += binB;
        unsigned short* vk0 = (unsigned short*)ws;  ws += vkB;
        unsigned short* vk1 = (unsigned short*)ws;  ws += vkB;
        _Float16* h0 = (_Float16*)ws;            ws += hB;
        _Float16* h1 = (_Float16*)ws;            ws += hB;
        wc1 = (_Float16*)ws;                     ws += wc1B;
        wc2 = (_Float16*)ws;                     ws += wc2B;
        int* bcnt0 = (int*)ws;                   ws += nbB;
        int* bcnt1 = (int*)ws;                   // contiguous with bcnt0

        G g0{x1, ei1, ei1 + E, bcnt0, bin0, u0, vk0, h0, out};
        G g1{x2, ei2, ei2 + E, bcnt1, bin1, u1, vk1, h1, out + (size_t)N * HID};
        prep_w_kernel<<<pBlk, 256, 0, stream>>>(W1, W2, wc1, wc2, vk0, vk1, N);
        run(g0, g1, 2);
    } else {
        // sequential fallback (~34 MB): one graph's buffers, reused
        float* u = (float*)ws;                   ws += rowB;
        unsigned int* bin = (unsigned int*)ws;   ws += binB;
        unsigned short* vk = (unsigned short*)ws;  ws += vkB;
        _Float16* h = (_Float16*)ws;             ws += hB;
        wc1 = (_Float16*)ws;                     ws += wc1B;
        wc2 = (_Float16*)ws;                     ws += wc2B;
        int* bcnt = (int*)ws;

        prep_w_kernel<<<pBlk, 256, 0, stream>>>(W1, W2, wc1, wc2, vk, vk, N);
        for (int g = 0; g < 2; ++g) {
            const int* ei = g ? ei2 : ei1;
            G gp{g ? x2 : x1, ei, ei + E, bcnt, bin,
                 u, vk, h, out + (size_t)g * N * HID};
            run(gp, gp, 1);
        }
    }
}

// Round 7
// 260.876 us; speedup vs baseline: 1.2447x; 1.0289x over previous
//
#include <hip/hip_runtime.h>
#include <hip/hip_fp16.h>

// SiameseEdgeConvNet: 2-layer EdgeConv (max aggr) on two graphs, shared weights.
// N=50000, E=1.6e6, dims 32 -> 64 -> 64.
//
// Algebra: msg = relu([xi, xj-xi] @ W + b) = relu(xi@A + xj@B + b),
//   A=W_lo-W_hi, B=W_hi.  u = x@A + b, v = x@B per node; ReLU monotone =>
//   out[d] = relu(u[d] + max_{e: dst=d} v[src_e]);  empty segment -> 0
//   (matches jax isfinite->0 fixup).  PReLU input >= 0 -> identity -> skipped.
//
// R19. Ledger (do NOT retry):
//   - R13 per-node global binning: 250 us (random 2B stores, 186 MB writes).
//   - R15 temporal half-row agg passes: working set unchanged, rows fetched
//     twice. FETCH 114->168 MB.
//   - R16 2 agg blocks/bucket: duplicate record scan, 55 us.
//   - R17 spatial channel-half x XCD: 64B half-gathers still pull full HBM
//     sectors from 2 XCDs -> vk HBM 2x. FETCH 195 MB, 86 us.
//   - R18 bin TILE=32/EPT=8: runs of 1.3 records -> full-line dirty per run,
//     68 us DESPITE occ 23->50%. Bin tracks RUN LENGTH, not occupancy:
//     {2.6 rec -> 47.7 us} {5.2 rec -> <55} {1.3 rec -> 68}.
// R19 changes:
//   * bin: TILE=128 (391 buckets) + 1024-thread blocks + EPT=4: 4096
//     edges/block -> runs ~10.5 rec = 42 B (~2.5x amp), grid 391/graph of
//     1024t = ~2 blocks/CU (full thread occupancy), LDS 4 KB.
//   * agg: 512-thread block per 128-bucket: SINGLE record scan, 24.5 KB LDS,
//     grid 782 -> ~3 blocks/CU x 8 waves = 75% occ (R15's failure was 256t
//     -> 12 waves/CU). Phase B: 32 groups x 16 lanes, 4 seq nodes, 16-deep
//     gather pipeline, sentinel-padded lists, fp16 h out (all R18-proven).
//   * gemm64 reads fp16 h (half traffic, no cvt); vk row N = -inf sentinel.

constexpr int HID   = 64;
constexpr int TILE  = 128;          // nodes per bucket (dst >> 7)
constexpr int TSH   = 7;            // log2(TILE)
constexpr int CAP   = 5120;         // records per bucket (mean 4096, +16s)
constexpr int MAXNB = 512;          // max buckets (N <= 65536)
constexpr int EPT   = 4;            // edges per thread in bin_kernel (1024t)
constexpr int CAPN  = 96;           // per-node capacity (mean deg 32, max ~70)

typedef _Float16 half8 __attribute__((ext_vector_type(8)));
typedef float    f32x4 __attribute__((ext_vector_type(4)));

__device__ __forceinline__ unsigned int pkmax(unsigned int a, unsigned int b) {
    unsigned int d;
    asm("v_pk_max_f16 %0, %1, %2" : "=v"(d) : "v"(a), "v"(b));
    return d;
}
__device__ __forceinline__ unsigned int f2hbits(float f) {
    const __half h = __float2half_rn(f);
    return (unsigned int)*reinterpret_cast<const unsigned short*>(&h);
}
__device__ __forceinline__ float h2f(unsigned int b16) {
    const unsigned short b = (unsigned short)b16;
    __half h;
    *reinterpret_cast<unsigned short*>(&h) = b;
    return __half2float(h);
}

struct G {                    // one graph's pointer set
    const float* x;           // [N,32] layer-1 input
    const int*   src;         // [E]
    const int*   dst;         // [E]
    int* bcnt;                // [NB]       bucket fill counters
    unsigned int* bin;        // [NB*CAP]   packed records (src<<7 | dst&127)
    float*          u;        // [N,64] fp32
    unsigned short* vk;       // [(N+1),64] fp16, permuted: uint2 slot m of a
                              //   row holds channels {m, m+16, m+32, m+48};
                              //   row N = -inf sentinel (set once in prep_w)
    _Float16*       h;        // [N,64] fp16 row-major — layer-1 output
    float*          out;      // [N,64] fp32 — final output
};

// ---- weight prep + vk sentinel row init ----
__global__ __launch_bounds__(256) void prep_w_kernel(
    const float* __restrict__ W1, const float* __restrict__ W2,
    _Float16* __restrict__ Wc1, _Float16* __restrict__ Wc2,
    unsigned short* __restrict__ vkS0, unsigned short* __restrict__ vkS1, int N)
{
    const int i = blockIdx.x * 256 + threadIdx.x;
    if (i < 32 * 64) {
        const int k = i >> 6, c = i & 63;
        const float lo = W1[k * 64 + c], hi = W1[(32 + k) * 64 + c];
        Wc1[k * 128 + c]      = (_Float16)(lo - hi);
        Wc1[k * 128 + 64 + c] = (_Float16)hi;
    }
    const int j = i - 32 * 64;
    if (j >= 0 && j < 64 * 64) {
        const int k = j >> 6, c = j & 63;
        const float lo = W2[k * 64 + c], hi = W2[(64 + k) * 64 + c];
        Wc2[k * 128 + c]      = (_Float16)(lo - hi);
        Wc2[k * 128 + 64 + c] = (_Float16)hi;
    }
    const int q = i - (32 * 64 + 64 * 64);
    if (q >= 0 && q < 2 * HID) {                 // sentinel rows = -inf fp16
        if (q < HID) vkS0[(size_t)N * HID + q]       = 0xFC00u;
        else         vkS1[(size_t)N * HID + (q-HID)] = 0xFC00u;
    }
}

// ---- bin: block-reserved capacity scatter, 1024 threads ----
__global__ __launch_bounds__(1024) void bin_kernel(G g0, G g1, int E, int NB) {
    const G g = blockIdx.y ? g1 : g0;
    __shared__ int lh[MAXNB];   // local hist, then local write offset
    __shared__ int lb[MAXNB];   // reserved base per bucket
    for (int i = threadIdx.x; i < NB; i += 1024) lh[i] = 0;
    __syncthreads();

    const int base = blockIdx.x * 1024 * EPT;
    unsigned int rec[EPT];
    int bb[EPT];
    #pragma unroll
    for (int k = 0; k < EPT; ++k) {
        const int i = base + k * 1024 + threadIdx.x;   // coalesced stream
        if (i < E) {
            const int d = g.dst[i];
            const int s = g.src[i];
            rec[k] = ((unsigned int)s << TSH) | (unsigned int)(d & (TILE - 1));
            bb[k]  = d >> TSH;
            atomicAdd(&lh[bb[k]], 1);
        } else bb[k] = -1;
    }
    __syncthreads();
    for (int t = threadIdx.x; t < NB; t += 1024) {
        const int c = lh[t];
        lb[t] = c ? atomicAdd(&g.bcnt[t], c) : 0;   // global range reservation
        lh[t] = 0;
    }
    __syncthreads();
    #pragma unroll
    for (int k = 0; k < EPT; ++k) {
        if (bb[k] >= 0) {
            const int off = atomicAdd(&lh[bb[k]], 1);
            const int pos = lb[bb[k]] + off;
            if (pos < CAP)                            // 16-sigma guard
                g.bin[(size_t)bb[k] * CAP + pos] = rec[k];
        }
    }
}

// ---- MFMA node GEMM: [u|v](N x 128) = in(N x K) @ Wc(K x 128); u += bias ----
// IN16=false: input = g.x fp32.  IN16=true (K=64): input = g.h fp16 row-major.
// v emitted as raw fp16, permuted: uint2 slot m of a row holds channels
// {m, m+16, m+32, m+48}.
template<int K, bool IN16>
__global__ __launch_bounds__(256) void gemm_mfma_kernel(
    G g0, G g1, const _Float16* __restrict__ Wc,
    const float* __restrict__ bias, int N)
{
    const G g = blockIdx.y ? g1 : g0;
    constexpr int KH = K / 32;                 // k-halves (1 or 2)
    const int lane = threadIdx.x & 63;
    const int m    = lane & 15;                // A row / D col-lane
    const int quad = lane >> 4;
    const int wid  = (blockIdx.x * 256 + threadIdx.x) >> 6;
    const int nW   = (gridDim.x * 256) >> 6;

    // B-frags: B[k=32h+quad*8+j][n=16t+m]
    half8 bf[8][KH];
    #pragma unroll
    for (int t = 0; t < 8; ++t)
        #pragma unroll
        for (int hh = 0; hh < KH; ++hh)
            #pragma unroll
            for (int j = 0; j < 8; ++j)
                bf[t][hh][j] = Wc[(hh * 32 + quad * 8 + j) * 128 + t * 16 + m];

    float bv[4];
    #pragma unroll
    for (int t = 0; t < 4; ++t) bv[t] = bias[t * 16 + m];

    const int tiles = (N + 15) / 16;

    for (int tile = wid; tile < tiles; tile += nW) {
        const int nbase = tile * 16;
        const int nodeA = min(nbase + m, N - 1);

        half8 a[KH];
        if constexpr (IN16) {
            const half8* rp = (const half8*)(g.h + (size_t)nodeA * K);
            #pragma unroll
            for (int hh = 0; hh < KH; ++hh) a[hh] = rp[hh * 4 + quad];
        } else {
            const float4* rp = (const float4*)(g.x + (size_t)nodeA * K);
            #pragma unroll
            for (int hh = 0; hh < KH; ++hh) {
                const float4 f0 = rp[hh * 8 + quad * 2];
                const float4 f1 = rp[hh * 8 + quad * 2 + 1];
                a[hh][0] = (_Float16)f0.x; a[hh][1] = (_Float16)f0.y;
                a[hh][2] = (_Float16)f0.z; a[hh][3] = (_Float16)f0.w;
                a[hh][4] = (_Float16)f1.x; a[hh][5] = (_Float16)f1.y;
                a[hh][6] = (_Float16)f1.z; a[hh][7] = (_Float16)f1.w;
            }
        }

        f32x4 acc[8];
        #pragma unroll
        for (int t = 0; t < 8; ++t) {
            acc[t] = (f32x4){0.f, 0.f, 0.f, 0.f};
            #pragma unroll
            for (int hh = 0; hh < KH; ++hh)
                acc[t] = __builtin_amdgcn_mfma_f32_16x16x32_f16(
                    a[hh], bf[t][hh], acc[t], 0, 0, 0);
        }

        // D[m=quad*4+r][n=lane&15]
        #pragma unroll
        for (int r = 0; r < 4; ++r) {
            const int node = nbase + quad * 4 + r;
            if (node < N) {
                float* urow = g.u + (size_t)node * HID;
                #pragma unroll
                for (int t = 0; t < 4; ++t)
                    urow[t * 16 + m] = acc[t][r] + bv[t];
                const unsigned int e0 = f2hbits(acc[4][r]);   // channel m
                const unsigned int e1 = f2hbits(acc[5][r]);   // channel m+16
                const unsigned int e2 = f2hbits(acc[6][r]);   // channel m+32
                const unsigned int e3 = f2hbits(acc[7][r]);   // channel m+48
                uint2 pack;
                pack.x = (e1 << 16) | e0;
                pack.y = (e3 << 16) | e2;
                ((uint2*)(g.vk + (size_t)node * HID))[m] = pack;
            }
        }
    }
}

// ---- aggregate: 512 threads per 128-node bucket, SINGLE scan ----
// Phase A: coalesced record read + LDS counting sort into per-node lists,
//   padded to multiples of 16 with sentinel src=N (-inf vk row).
// Phase B: 32 groups x 16 lanes, 4 sequential nodes/group; running max in
//   registers via v_pk_max_f16; full-row uint2 gathers, 16 in flight.
// OUT16=true (layer 1): write h fp16 row-major.  false: write fp32 out.
template<bool OUT16>
__global__ __launch_bounds__(512) void agg_kernel(G g0, G g1, int N, int NB, int two) {
    int b, gi;
    if (two) {                       // XCD partition: bid%8 -> XCD (heuristic)
        const int bid = blockIdx.x;
        const int xcd = bid & 7;
        gi = xcd >> 2;               // XCD 0-3: graph 0, XCD 4-7: graph 1
        b  = (bid >> 3) * 4 + (xcd & 3);
    } else { gi = 0; b = blockIdx.x; }
    if (b >= NB) return;
    const G g = gi ? g1 : g0;

    __shared__ int lcnt[TILE];
    __shared__ alignas(16) unsigned short lrec[TILE][CAPN];  // 24 KB
    for (int i = threadIdx.x; i < TILE; i += 512) lcnt[i] = 0;
    __syncthreads();

    const int cnt = min(g.bcnt[b], CAP);
    const unsigned int* __restrict__ bp = g.bin + (size_t)b * CAP;
    for (int i = threadIdx.x; i < cnt; i += 512) {
        const unsigned int rec = bp[i];
        const int d = rec & (TILE - 1);
        const int p = atomicAdd(&lcnt[d], 1);
        if (p < CAPN) lrec[d][p] = (unsigned short)(rec >> TSH);
    }
    __syncthreads();
    for (int t = threadIdx.x; t < TILE; t += 512) {   // pad to x16 w/ sentinel
        const int c  = min(lcnt[t], CAPN);
        const int cp = (c + 15) & ~15;
        for (int p = c; p < cp; ++p) lrec[t][p] = (unsigned short)N;
        lcnt[t] = cp;
    }
    __syncthreads();

    const int grp = threadIdx.x >> 4;        // 32 groups of 16 lanes
    const int sub = threadIdx.x & 15;
    const uint2* __restrict__ vk2 = (const uint2*)g.vk;

    #pragma unroll
    for (int i = 0; i < 4; ++i) {
        const int nl = grp + 32 * i;
        const int n  = b * TILE + nl;
        if (n >= N) continue;
        const int cp = lcnt[nl];

        unsigned int m0 = 0xFC00FC00u, m1 = 0xFC00FC00u;   // -inf halves
        for (int j = 0; j < cp; j += 16) {
            const uint4 q0 = *(const uint4*)(&lrec[nl][j]);      // 16 recs,
            const uint4 q1 = *(const uint4*)(&lrec[nl][j + 8]);  // bcast
            unsigned int s[16];
            s[0]  = q0.x & 0xFFFFu; s[1]  = q0.x >> 16;
            s[2]  = q0.y & 0xFFFFu; s[3]  = q0.y >> 16;
            s[4]  = q0.z & 0xFFFFu; s[5]  = q0.z >> 16;
            s[6]  = q0.w & 0xFFFFu; s[7]  = q0.w >> 16;
            s[8]  = q1.x & 0xFFFFu; s[9]  = q1.x >> 16;
            s[10] = q1.y & 0xFFFFu; s[11] = q1.y >> 16;
            s[12] = q1.z & 0xFFFFu; s[13] = q1.z >> 16;
            s[14] = q1.w & 0xFFFFu; s[15] = q1.w >> 16;
            uint2 a[16];
            #pragma unroll
            for (int k = 0; k < 16; ++k) a[k] = vk2[(size_t)s[k] * 16 + sub];
            #pragma unroll
            for (int k = 0; k < 16; ++k) {
                m0 = pkmax(m0, a[k].x);
                m1 = pkmax(m1, a[k].y);
            }
        }

        const bool has = cp > 0;
        const float* __restrict__ urow = g.u + (size_t)n * HID;
        const float r0 = has ? fmaxf(urow[sub]      + h2f(m0 & 0xFFFFu), 0.f) : 0.f;
        const float r1 = has ? fmaxf(urow[sub + 16] + h2f(m0 >> 16),     0.f) : 0.f;
        const float r2 = has ? fmaxf(urow[sub + 32] + h2f(m1 & 0xFFFFu), 0.f) : 0.f;
        const float r3 = has ? fmaxf(urow[sub + 48] + h2f(m1 >> 16),     0.f) : 0.f;
        if constexpr (OUT16) {       // fp16 h, same rounding gemm64 would do
            _Float16* hrow = g.h + (size_t)n * HID;
            hrow[sub]      = (_Float16)r0;
            hrow[sub + 16] = (_Float16)r1;
            hrow[sub + 32] = (_Float16)r2;
            hrow[sub + 48] = (_Float16)r3;
        } else {
            float* __restrict__ orow = g.out + (size_t)n * HID;
            orow[sub]      = r0;
            orow[sub + 16] = r1;
            orow[sub + 32] = r2;
            orow[sub + 48] = r3;
        }
    }
}

// ---------------- orchestration ----------------

extern "C" void kernel_launch(void* const* d_in, const int* in_sizes, int n_in,
                              void* d_out, int out_size, void* d_ws, size_t ws_size,
                              hipStream_t stream) {
    const float* x1  = (const float*)d_in[0];
    const int*   ei1 = (const int*)d_in[1];   // [2,E]: src row then dst row
    const float* x2  = (const float*)d_in[2];
    const int*   ei2 = (const int*)d_in[3];
    const float* W1  = (const float*)d_in[4];
    const float* b1  = (const float*)d_in[5];
    // d_in[6] = prelu_a: unused (identity on >=0)
    const float* W2  = (const float*)d_in[7];
    const float* b2  = (const float*)d_in[8];

    const int N  = in_sizes[0] / 32;
    const int E  = in_sizes[1] / 2;
    const int NB = (N + TILE - 1) / TILE;     // 391 for N=50000
    float* out = (float*)d_out;

    const size_t rowB = (size_t)N * HID * sizeof(float);            // 12.8 MB
    const size_t vkB  = ((size_t)(N + 1) * HID * 2 + 63) & ~(size_t)63;
    const size_t hB   = ((size_t)N * HID * 2 + 63) & ~(size_t)63;   //  6.4 MB
    const size_t binB = ((size_t)NB * CAP * sizeof(int) + 63) & ~(size_t)63;
    const size_t nbB  = ((size_t)(NB + 2) * sizeof(int) + 63) & ~(size_t)63;
    const size_t wc1B = ((size_t)32 * 128 * 2 + 63) & ~(size_t)63;
    const size_t wc2B = ((size_t)64 * 128 * 2 + 63) & ~(size_t)63;

    const int bBlk = (E + 1024 * EPT - 1) / (1024 * EPT);   // 391 per graph
    const int gBlk = 512;
    const int pBlk = (32 * 64 + 64 * 64 + 2 * HID + 255) / 256;
    const int aggBlk2 = ((NB + 3) / 4) * 8;   // XCD-partitioned 1D grid
    const int aggBlk1 = NB;

    _Float16* wc1 = nullptr;
    _Float16* wc2 = nullptr;

    auto run = [&](G ga, G gb, int ny) {
        // bcnt arrays contiguous across graphs: one memset when ny==2
        hipMemsetAsync(ga.bcnt, 0, (size_t)ny * nbB, stream);
        bin_kernel <<<dim3(bBlk, ny), 1024, 0, stream>>>(ga, gb, E, NB);
        gemm_mfma_kernel<32,false><<<dim3(gBlk, ny), 256, 0, stream>>>(ga, gb, wc1, b1, N);
        if (ny == 2) agg_kernel<true><<<aggBlk2, 512, 0, stream>>>(ga, gb, N, NB, 1);
        else         agg_kernel<true><<<aggBlk1, 512, 0, stream>>>(ga, ga, N, NB, 0);
        gemm_mfma_kernel<64,true><<<dim3(gBlk, ny), 256, 0, stream>>>(ga, gb, wc2, b2, N);
        if (ny == 2) agg_kernel<false><<<aggBlk2, 512, 0, stream>>>(ga, gb, N, NB, 1);
        else         agg_kernel<false><<<aggBlk1, 512, 0, stream>>>(ga, ga, N, NB, 0);
    };

    char* ws = (char*)d_ws;
    const size_t needBoth =
        2 * rowB + 2 * binB + 2 * vkB + 2 * hB + wc1B + wc2B + 2 * nbB;

    if (ws_size >= needBoth) {
        float* u0 = (float*)ws;                  ws += rowB;
        float* u1 = (float*)ws;                  ws += rowB;
        unsigned int* bin0 = (unsigned int*)ws;  ws += binB;
        unsigned int* bin1 = (unsigned int*)ws;  ws += binB;
        unsigned short* vk0 = (unsigned short*)ws;  ws += vkB;
        unsigned short* vk1 = (unsigned short*)ws;  ws += vkB;
        _Float16* h0 = (_Float16*)ws;            ws += hB;
        _Float16* h1 = (_Float16*)ws;            ws += hB;
        wc1 = (_Float16*)ws;                     ws += wc1B;
        wc2 = (_Float16*)ws;                     ws += wc2B;
        int* bcnt0 = (int*)ws;                   ws += nbB;
        int* bcnt1 = (int*)ws;                   // contiguous with bcnt0

        G g0{x1, ei1, ei1 + E, bcnt0, bin0, u0, vk0, h0, out};
        G g1{x2, ei2, ei2 + E, bcnt1, bin1, u1, vk1, h1, out + (size_t)N * HID};
        prep_w_kernel<<<pBlk, 256, 0, stream>>>(W1, W2, wc1, wc2, vk0, vk1, N);
        run(g0, g1, 2);
    } else {
        // sequential fallback (~34 MB): one graph's buffers, reused
        float* u = (float*)ws;                   ws += rowB;
        unsigned int* bin = (unsigned int*)ws;   ws += binB;
        unsigned short* vk = (unsigned short*)ws;  ws += vkB;
        _Float16* h = (_Float16*)ws;             ws += hB;
        wc1 = (_Float16*)ws;                     ws += wc1B;
        wc2 = (_Float16*)ws;                     ws += wc2B;
        int* bcnt = (int*)ws;

        prep_w_kernel<<<pBlk, 256, 0, stream>>>(W1, W2, wc1, wc2, vk, vk, N);
        for (int g = 0; g < 2; ++g) {
            const int* ei = g ? ei2 : ei1;
            G gp{g ? x2 : x1, ei, ei + E, bcnt, bin,
                 u, vk, h, out + (size_t)g * N * HID};
            run(gp, gp, 1);
        }
    }
}

// Round 8
// 252.169 us; speedup vs baseline: 1.2876x; 1.0345x over previous
//
#include <hip/hip_runtime.h>
#include <hip/hip_fp16.h>

// SiameseEdgeConvNet: 2-layer EdgeConv (max aggr) on two graphs, shared weights.
// N=50000, E=1.6e6, dims 32 -> 64 -> 64.
//
// Algebra: msg = relu([xi, xj-xi] @ W + b) = relu(xi@A + xj@B + b),
//   A=W_lo-W_hi, B=W_hi.  u = x@A + b, v = x@B per node; ReLU monotone =>
//   out[d] = relu(u[d] + max_{e: dst=d} v[src_e]);  empty segment -> 0
//   (matches jax isfinite->0 fixup).  PReLU input >= 0 -> identity -> skipped.
//
// R20. Ledger (do NOT retry):
//   - R13 per-node global binning: 250 us (random 2B stores, 186 MB writes).
//   - R15 temporal half-row agg passes: FETCH 114->168 MB.
//   - R16 2 agg blocks/bucket: duplicate record scan, 55 us.
//   - R17 spatial channel-half x XCD: vk HBM 2x, FETCH 195 MB, 86 us.
//   - R18 bin short runs (1.3 rec): 68 us despite occ 2x. Bin tracks RUN
//     LENGTH: {1.3 rec -> 68} {2.6 -> 47.7} {5.2 -> <55} {10.5 -> <59}.
//   - R19 agg 512t/25KB blocks: occ 40.7% -> 59.5 us. Agg tracks OCCUPANCY
//     at fixed FETCH~114MB: {57% -> 48} {48% -> 55} {41% -> 59.5}. Agg is
//     latency-bound on divergent gathers (~9-12 cyc/record).
// R20: TILE=64 satisfies both: bin runs 5.2 rec (1024t EPT=4 blocks), agg
//   256t/12.9KB blocks grid 1564 = 6.1/CU -> ~24 waves/CU (75%), single
//   scan, R14-proven phase B (16-deep uint2 gather pipeline, sentinel pad,
//   fp16 h out). If agg stays ~48 at occ>=70%, gather machinery saturated.

constexpr int HID   = 64;
constexpr int TILE  = 64;           // nodes per bucket (dst >> 6)
constexpr int TSH   = 6;            // log2(TILE)
constexpr int CAP   = 2560;         // records per bucket (mean 2048, +11s)
constexpr int MAXNB = 1024;         // max buckets (N <= 65536)
constexpr int EPT   = 4;            // edges per thread in bin_kernel (1024t)
constexpr int CAPN  = 96;           // per-node capacity (mean deg 32, max ~62)

typedef _Float16 half8 __attribute__((ext_vector_type(8)));
typedef float    f32x4 __attribute__((ext_vector_type(4)));

__device__ __forceinline__ unsigned int pkmax(unsigned int a, unsigned int b) {
    unsigned int d;
    asm("v_pk_max_f16 %0, %1, %2" : "=v"(d) : "v"(a), "v"(b));
    return d;
}
__device__ __forceinline__ unsigned int f2hbits(float f) {
    const __half h = __float2half_rn(f);
    return (unsigned int)*reinterpret_cast<const unsigned short*>(&h);
}
__device__ __forceinline__ float h2f(unsigned int b16) {
    const unsigned short b = (unsigned short)b16;
    __half h;
    *reinterpret_cast<unsigned short*>(&h) = b;
    return __half2float(h);
}

struct G {                    // one graph's pointer set
    const float* x;           // [N,32] layer-1 input
    const int*   src;         // [E]
    const int*   dst;         // [E]
    int* bcnt;                // [NB]       bucket fill counters
    unsigned int* bin;        // [NB*CAP]   packed records (src<<6 | dst&63)
    float*          u;        // [N,64] fp32
    unsigned short* vk;       // [(N+1),64] fp16, permuted: uint2 slot m of a
                              //   row holds channels {m, m+16, m+32, m+48};
                              //   row N = -inf sentinel (set once in prep_w)
    _Float16*       h;        // [N,64] fp16 row-major — layer-1 output
    float*          out;      // [N,64] fp32 — final output
};

// ---- weight prep + vk sentinel row init ----
__global__ __launch_bounds__(256) void prep_w_kernel(
    const float* __restrict__ W1, const float* __restrict__ W2,
    _Float16* __restrict__ Wc1, _Float16* __restrict__ Wc2,
    unsigned short* __restrict__ vkS0, unsigned short* __restrict__ vkS1, int N)
{
    const int i = blockIdx.x * 256 + threadIdx.x;
    if (i < 32 * 64) {
        const int k = i >> 6, c = i & 63;
        const float lo = W1[k * 64 + c], hi = W1[(32 + k) * 64 + c];
        Wc1[k * 128 + c]      = (_Float16)(lo - hi);
        Wc1[k * 128 + 64 + c] = (_Float16)hi;
    }
    const int j = i - 32 * 64;
    if (j >= 0 && j < 64 * 64) {
        const int k = j >> 6, c = j & 63;
        const float lo = W2[k * 64 + c], hi = W2[(64 + k) * 64 + c];
        Wc2[k * 128 + c]      = (_Float16)(lo - hi);
        Wc2[k * 128 + 64 + c] = (_Float16)hi;
    }
    const int q = i - (32 * 64 + 64 * 64);
    if (q >= 0 && q < 2 * HID) {                 // sentinel rows = -inf fp16
        if (q < HID) vkS0[(size_t)N * HID + q]       = 0xFC00u;
        else         vkS1[(size_t)N * HID + (q-HID)] = 0xFC00u;
    }
}

// ---- bin: block-reserved capacity scatter, 1024 threads ----
__global__ __launch_bounds__(1024) void bin_kernel(G g0, G g1, int E, int NB) {
    const G g = blockIdx.y ? g1 : g0;
    __shared__ int lh[MAXNB];   // local hist, then local write offset
    __shared__ int lb[MAXNB];   // reserved base per bucket
    for (int i = threadIdx.x; i < NB; i += 1024) lh[i] = 0;
    __syncthreads();

    const int base = blockIdx.x * 1024 * EPT;
    unsigned int rec[EPT];
    int bb[EPT];
    #pragma unroll
    for (int k = 0; k < EPT; ++k) {
        const int i = base + k * 1024 + threadIdx.x;   // coalesced stream
        if (i < E) {
            const int d = g.dst[i];
            const int s = g.src[i];
            rec[k] = ((unsigned int)s << TSH) | (unsigned int)(d & (TILE - 1));
            bb[k]  = d >> TSH;
            atomicAdd(&lh[bb[k]], 1);
        } else bb[k] = -1;
    }
    __syncthreads();
    for (int t = threadIdx.x; t < NB; t += 1024) {
        const int c = lh[t];
        lb[t] = c ? atomicAdd(&g.bcnt[t], c) : 0;   // global range reservation
        lh[t] = 0;
    }
    __syncthreads();
    #pragma unroll
    for (int k = 0; k < EPT; ++k) {
        if (bb[k] >= 0) {
            const int off = atomicAdd(&lh[bb[k]], 1);
            const int pos = lb[bb[k]] + off;
            if (pos < CAP)                            // 11-sigma guard
                g.bin[(size_t)bb[k] * CAP + pos] = rec[k];
        }
    }
}

// ---- MFMA node GEMM: [u|v](N x 128) = in(N x K) @ Wc(K x 128); u += bias ----
// IN16=false: input = g.x fp32.  IN16=true (K=64): input = g.h fp16 row-major.
// v emitted as raw fp16, permuted: uint2 slot m of a row holds channels
// {m, m+16, m+32, m+48}.
template<int K, bool IN16>
__global__ __launch_bounds__(256) void gemm_mfma_kernel(
    G g0, G g1, const _Float16* __restrict__ Wc,
    const float* __restrict__ bias, int N)
{
    const G g = blockIdx.y ? g1 : g0;
    constexpr int KH = K / 32;                 // k-halves (1 or 2)
    const int lane = threadIdx.x & 63;
    const int m    = lane & 15;                // A row / D col-lane
    const int quad = lane >> 4;
    const int wid  = (blockIdx.x * 256 + threadIdx.x) >> 6;
    const int nW   = (gridDim.x * 256) >> 6;

    // B-frags: B[k=32h+quad*8+j][n=16t+m]
    half8 bf[8][KH];
    #pragma unroll
    for (int t = 0; t < 8; ++t)
        #pragma unroll
        for (int hh = 0; hh < KH; ++hh)
            #pragma unroll
            for (int j = 0; j < 8; ++j)
                bf[t][hh][j] = Wc[(hh * 32 + quad * 8 + j) * 128 + t * 16 + m];

    float bv[4];
    #pragma unroll
    for (int t = 0; t < 4; ++t) bv[t] = bias[t * 16 + m];

    const int tiles = (N + 15) / 16;

    for (int tile = wid; tile < tiles; tile += nW) {
        const int nbase = tile * 16;
        const int nodeA = min(nbase + m, N - 1);

        half8 a[KH];
        if constexpr (IN16) {
            const half8* rp = (const half8*)(g.h + (size_t)nodeA * K);
            #pragma unroll
            for (int hh = 0; hh < KH; ++hh) a[hh] = rp[hh * 4 + quad];
        } else {
            const float4* rp = (const float4*)(g.x + (size_t)nodeA * K);
            #pragma unroll
            for (int hh = 0; hh < KH; ++hh) {
                const float4 f0 = rp[hh * 8 + quad * 2];
                const float4 f1 = rp[hh * 8 + quad * 2 + 1];
                a[hh][0] = (_Float16)f0.x; a[hh][1] = (_Float16)f0.y;
                a[hh][2] = (_Float16)f0.z; a[hh][3] = (_Float16)f0.w;
                a[hh][4] = (_Float16)f1.x; a[hh][5] = (_Float16)f1.y;
                a[hh][6] = (_Float16)f1.z; a[hh][7] = (_Float16)f1.w;
            }
        }

        f32x4 acc[8];
        #pragma unroll
        for (int t = 0; t < 8; ++t) {
            acc[t] = (f32x4){0.f, 0.f, 0.f, 0.f};
            #pragma unroll
            for (int hh = 0; hh < KH; ++hh)
                acc[t] = __builtin_amdgcn_mfma_f32_16x16x32_f16(
                    a[hh], bf[t][hh], acc[t], 0, 0, 0);
        }

        // D[m=quad*4+r][n=lane&15]
        #pragma unroll
        for (int r = 0; r < 4; ++r) {
            const int node = nbase + quad * 4 + r;
            if (node < N) {
                float* urow = g.u + (size_t)node * HID;
                #pragma unroll
                for (int t = 0; t < 4; ++t)
                    urow[t * 16 + m] = acc[t][r] + bv[t];
                const unsigned int e0 = f2hbits(acc[4][r]);   // channel m
                const unsigned int e1 = f2hbits(acc[5][r]);   // channel m+16
                const unsigned int e2 = f2hbits(acc[6][r]);   // channel m+32
                const unsigned int e3 = f2hbits(acc[7][r]);   // channel m+48
                uint2 pack;
                pack.x = (e1 << 16) | e0;
                pack.y = (e3 << 16) | e2;
                ((uint2*)(g.vk + (size_t)node * HID))[m] = pack;
            }
        }
    }
}

// ---- aggregate: 256 threads per 64-node bucket, SINGLE scan ----
// Phase A: coalesced record read + LDS counting sort into per-node lists,
//   padded to multiples of 16 with sentinel src=N (-inf vk row).
// Phase B: 16 groups x 16 lanes, 4 sequential nodes/group; running max in
//   registers via v_pk_max_f16; full-row uint2 gathers, 16 in flight.
// OUT16=true (layer 1): write h fp16 row-major.  false: write fp32 out.
template<bool OUT16>
__global__ __launch_bounds__(256) void agg_kernel(G g0, G g1, int N, int NB, int two) {
    int b, gi;
    if (two) {                       // XCD partition: bid%8 -> XCD (heuristic)
        const int bid = blockIdx.x;
        const int xcd = bid & 7;
        gi = xcd >> 2;               // XCD 0-3: graph 0, XCD 4-7: graph 1
        b  = (bid >> 3) * 4 + (xcd & 3);
    } else { gi = 0; b = blockIdx.x; }
    if (b >= NB) return;
    const G g = gi ? g1 : g0;

    __shared__ int lcnt[TILE];
    __shared__ alignas(16) unsigned short lrec[TILE][CAPN];  // 12.3 KB
    for (int i = threadIdx.x; i < TILE; i += 256) lcnt[i] = 0;
    __syncthreads();

    const int cnt = min(g.bcnt[b], CAP);
    const unsigned int* __restrict__ bp = g.bin + (size_t)b * CAP;
    for (int i = threadIdx.x; i < cnt; i += 256) {
        const unsigned int rec = bp[i];
        const int d = rec & (TILE - 1);
        const int p = atomicAdd(&lcnt[d], 1);
        if (p < CAPN) lrec[d][p] = (unsigned short)(rec >> TSH);
    }
    __syncthreads();
    for (int t = threadIdx.x; t < TILE; t += 256) {   // pad to x16 w/ sentinel
        const int c  = min(lcnt[t], CAPN);
        const int cp = (c + 15) & ~15;
        for (int p = c; p < cp; ++p) lrec[t][p] = (unsigned short)N;
        lcnt[t] = cp;
    }
    __syncthreads();

    const int grp = threadIdx.x >> 4;        // 16 groups of 16 lanes
    const int sub = threadIdx.x & 15;
    const uint2* __restrict__ vk2 = (const uint2*)g.vk;

    #pragma unroll
    for (int i = 0; i < 4; ++i) {
        const int nl = grp + 16 * i;
        const int n  = b * TILE + nl;
        if (n >= N) continue;
        const int cp = lcnt[nl];

        unsigned int m0 = 0xFC00FC00u, m1 = 0xFC00FC00u;   // -inf halves
        for (int j = 0; j < cp; j += 16) {
            const uint4 q0 = *(const uint4*)(&lrec[nl][j]);      // 16 recs,
            const uint4 q1 = *(const uint4*)(&lrec[nl][j + 8]);  // bcast
            unsigned int s[16];
            s[0]  = q0.x & 0xFFFFu; s[1]  = q0.x >> 16;
            s[2]  = q0.y & 0xFFFFu; s[3]  = q0.y >> 16;
            s[4]  = q0.z & 0xFFFFu; s[5]  = q0.z >> 16;
            s[6]  = q0.w & 0xFFFFu; s[7]  = q0.w >> 16;
            s[8]  = q1.x & 0xFFFFu; s[9]  = q1.x >> 16;
            s[10] = q1.y & 0xFFFFu; s[11] = q1.y >> 16;
            s[12] = q1.z & 0xFFFFu; s[13] = q1.z >> 16;
            s[14] = q1.w & 0xFFFFu; s[15] = q1.w >> 16;
            uint2 a[16];
            #pragma unroll
            for (int k = 0; k < 16; ++k) a[k] = vk2[(size_t)s[k] * 16 + sub];
            #pragma unroll
            for (int k = 0; k < 16; ++k) {
                m0 = pkmax(m0, a[k].x);
                m1 = pkmax(m1, a[k].y);
            }
        }

        const bool has = cp > 0;
        const float* __restrict__ urow = g.u + (size_t)n * HID;
        const float r0 = has ? fmaxf(urow[sub]      + h2f(m0 & 0xFFFFu), 0.f) : 0.f;
        const float r1 = has ? fmaxf(urow[sub + 16] + h2f(m0 >> 16),     0.f) : 0.f;
        const float r2 = has ? fmaxf(urow[sub + 32] + h2f(m1 & 0xFFFFu), 0.f) : 0.f;
        const float r3 = has ? fmaxf(urow[sub + 48] + h2f(m1 >> 16),     0.f) : 0.f;
        if constexpr (OUT16) {       // fp16 h, same rounding gemm64 would do
            _Float16* hrow = g.h + (size_t)n * HID;
            hrow[sub]      = (_Float16)r0;
            hrow[sub + 16] = (_Float16)r1;
            hrow[sub + 32] = (_Float16)r2;
            hrow[sub + 48] = (_Float16)r3;
        } else {
            float* __restrict__ orow = g.out + (size_t)n * HID;
            orow[sub]      = r0;
            orow[sub + 16] = r1;
            orow[sub + 32] = r2;
            orow[sub + 48] = r3;
        }
    }
}

// ---------------- orchestration ----------------

extern "C" void kernel_launch(void* const* d_in, const int* in_sizes, int n_in,
                              void* d_out, int out_size, void* d_ws, size_t ws_size,
                              hipStream_t stream) {
    const float* x1  = (const float*)d_in[0];
    const int*   ei1 = (const int*)d_in[1];   // [2,E]: src row then dst row
    const float* x2  = (const float*)d_in[2];
    const int*   ei2 = (const int*)d_in[3];
    const float* W1  = (const float*)d_in[4];
    const float* b1  = (const float*)d_in[5];
    // d_in[6] = prelu_a: unused (identity on >=0)
    const float* W2  = (const float*)d_in[7];
    const float* b2  = (const float*)d_in[8];

    const int N  = in_sizes[0] / 32;
    const int E  = in_sizes[1] / 2;
    const int NB = (N + TILE - 1) / TILE;     // 782 for N=50000
    float* out = (float*)d_out;

    const size_t rowB = (size_t)N * HID * sizeof(float);            // 12.8 MB
    const size_t vkB  = ((size_t)(N + 1) * HID * 2 + 63) & ~(size_t)63;
    const size_t hB   = ((size_t)N * HID * 2 + 63) & ~(size_t)63;   //  6.4 MB
    const size_t binB = ((size_t)NB * CAP * sizeof(int) + 63) & ~(size_t)63;
    const size_t nbB  = ((size_t)(NB + 2) * sizeof(int) + 63) & ~(size_t)63;
    const size_t wc1B = ((size_t)32 * 128 * 2 + 63) & ~(size_t)63;
    const size_t wc2B = ((size_t)64 * 128 * 2 + 63) & ~(size_t)63;

    const int bBlk = (E + 1024 * EPT - 1) / (1024 * EPT);   // 391 per graph
    const int gBlk = 512;
    const int pBlk = (32 * 64 + 64 * 64 + 2 * HID + 255) / 256;
    const int aggBlk2 = ((NB + 3) / 4) * 8;   // XCD-partitioned 1D grid
    const int aggBlk1 = NB;

    _Float16* wc1 = nullptr;
    _Float16* wc2 = nullptr;

    auto run = [&](G ga, G gb, int ny) {
        // bcnt arrays contiguous across graphs: one memset when ny==2
        hipMemsetAsync(ga.bcnt, 0, (size_t)ny * nbB, stream);
        bin_kernel <<<dim3(bBlk, ny), 1024, 0, stream>>>(ga, gb, E, NB);
        gemm_mfma_kernel<32,false><<<dim3(gBlk, ny), 256, 0, stream>>>(ga, gb, wc1, b1, N);
        if (ny == 2) agg_kernel<true><<<aggBlk2, 256, 0, stream>>>(ga, gb, N, NB, 1);
        else         agg_kernel<true><<<aggBlk1, 256, 0, stream>>>(ga, ga, N, NB, 0);
        gemm_mfma_kernel<64,true><<<dim3(gBlk, ny), 256, 0, stream>>>(ga, gb, wc2, b2, N);
        if (ny == 2) agg_kernel<false><<<aggBlk2, 256, 0, stream>>>(ga, gb, N, NB, 1);
        else         agg_kernel<false><<<aggBlk1, 256, 0, stream>>>(ga, ga, N, NB, 0);
    };

    char* ws = (char*)d_ws;
    const size_t needBoth =
        2 * rowB + 2 * binB + 2 * vkB + 2 * hB + wc1B + wc2B + 2 * nbB;

    if (ws_size >= needBoth) {
        float* u0 = (float*)ws;                  ws += rowB;
        float* u1 = (float*)ws;                  ws += rowB;
        unsigned int* bin0 = (unsigned int*)ws;  ws += binB;
        unsigned int* bin1 = (unsigned int*)ws;  ws += binB;
        unsigned short* vk0 = (unsigned short*)ws;  ws += vkB;
        unsigned short* vk1 = (unsigned short*)ws;  ws += vkB;
        _Float16* h0 = (_Float16*)ws;            ws += hB;
        _Float16* h1 = (_Float16*)ws;            ws += hB;
        wc1 = (_Float16*)ws;                     ws += wc1B;
        wc2 = (_Float16*)ws;                     ws += wc2B;
        int* bcnt0 = (int*)ws;                   ws += nbB;
        int* bcnt1 = (int*)ws;                   // contiguous with bcnt0

        G g0{x1, ei1, ei1 + E, bcnt0, bin0, u0, vk0, h0, out};
        G g1{x2, ei2, ei2 + E, bcnt1, bin1, u1, vk1, h1, out + (size_t)N * HID};
        prep_w_kernel<<<pBlk, 256, 0, stream>>>(W1, W2, wc1, wc2, vk0, vk1, N);
        run(g0, g1, 2);
    } else {
        // sequential fallback (~34 MB): one graph's buffers, reused
        float* u = (float*)ws;                   ws += rowB;
        unsigned int* bin = (unsigned int*)ws;   ws += binB;
        unsigned short* vk = (unsigned short*)ws;  ws += vkB;
        _Float16* h = (_Float16*)ws;             ws += hB;
        wc1 = (_Float16*)ws;                     ws += wc1B;
        wc2 = (_Float16*)ws;                     ws += wc2B;
        int* bcnt = (int*)ws;

        prep_w_kernel<<<pBlk, 256, 0, stream>>>(W1, W2, wc1, wc2, vk, vk, N);
        for (int g = 0; g < 2; ++g) {
            const int* ei = g ? ei2 : ei1;
            G gp{g ? x2 : x1, ei, ei + E, bcnt, bin,
                 u, vk, h, out + (size_t)g * N * HID};
            run(gp, gp, 1);
        }
    }
}